// Round 1
// baseline (568.978 us; speedup 1.0000x reference)
//
#include <hip/hip_runtime.h>
#include <hip/hip_bf16.h>
#include <math.h>

#define DEV static __device__ __forceinline__

typedef __attribute__((ext_vector_type(4))) float f32x4;
typedef __attribute__((ext_vector_type(8))) __bf16 bf16x8;
typedef __attribute__((ext_vector_type(8))) short s16x8;

DEV float b2f(short v){ unsigned u = ((unsigned)(unsigned short)v) << 16; float f; __builtin_memcpy(&f, &u, 4); return f; }
DEV short f2b(float f){ unsigned u; __builtin_memcpy(&u, &f, 4); unsigned r = (u + 0x7fffu + ((u >> 16) & 1u)) >> 16; return (short)r; }
DEV float gelu_f(float v){ return 0.5f * v * (1.0f + erff(v * 0.70710678118654752f)); }

// ---------------- generic cast fp32 -> bf16 (n % 8 == 0) ----------------
__global__ __launch_bounds__(256) void k_cast(const float* __restrict__ in, short* __restrict__ out, int n){
  int i = (blockIdx.x * 256 + threadIdx.x) * 8;
  if (i >= n) return;
  f32x4 a = *(const f32x4*)&in[i];
  f32x4 b = *(const f32x4*)&in[i + 4];
  s16x8 o;
  o[0]=f2b(a[0]); o[1]=f2b(a[1]); o[2]=f2b(a[2]); o[3]=f2b(a[3]);
  o[4]=f2b(b[0]); o[5]=f2b(b[1]); o[6]=f2b(b[2]); o[7]=f2b(b[3]);
  *(s16x8*)&out[i] = o;
}

// ---------------- transpose-cast: W[K][N] fp32 -> Wt[N][K] bf16 (dims %32==0) ----------------
__global__ __launch_bounds__(256) void k_tcast(const float* __restrict__ W, short* __restrict__ Wt, int K, int N){
  __shared__ float tile[32][33];
  int nb = blockIdx.x * 32, kb = blockIdx.y * 32;
  int tid = threadIdx.x;
  int c = tid & 31, r0 = tid >> 5;
  #pragma unroll
  for (int r = r0; r < 32; r += 8) tile[r][c] = W[(size_t)(kb + r) * N + nb + c];
  __syncthreads();
  #pragma unroll
  for (int r = r0; r < 32; r += 8) Wt[(size_t)(nb + r) * K + kb + c] = f2b(tile[c][r]);
}

// ---------------- GEMM core: per-wave acc = A[m0:m0+128, :K] * Bt[n0:n0+128, :K]^T ----------------
DEV void gemm_core(const short* __restrict__ A, const short* __restrict__ Bt,
                   int K, int lda, int ldb, int m0, int n0,
                   short* lA, short* lB, f32x4 acc[4][4])
{
  const int tid = threadIdx.x;
  const int lane = tid & 63;
  const int w = tid >> 6;
  const int wr = (w >> 1) * 64, wc = (w & 1) * 64;
  const int lr = lane & 15, lk = (lane >> 4) * 8;
  for (int kt = 0; kt < K; kt += 64) {
    __syncthreads();
    #pragma unroll
    for (int i = 0; i < 4; ++i) {
      int idx = (i * 256 + tid) * 8;
      int r = idx >> 6, c = idx & 63;
      *(s16x8*)&lA[r*64 + c] = *(const s16x8*)&A[(size_t)(m0 + r) * lda + kt + c];
      *(s16x8*)&lB[r*64 + c] = *(const s16x8*)&Bt[(size_t)(n0 + r) * ldb + kt + c];
    }
    __syncthreads();
    #pragma unroll
    for (int kk = 0; kk < 64; kk += 32) {
      bf16x8 af[4], bfr[4];
      #pragma unroll
      for (int mi = 0; mi < 4; ++mi) af[mi] = *(bf16x8*)&lA[(wr + mi*16 + lr)*64 + kk + lk];
      #pragma unroll
      for (int ni = 0; ni < 4; ++ni) bfr[ni] = *(bf16x8*)&lB[(wc + ni*16 + lr)*64 + kk + lk];
      #pragma unroll
      for (int mi = 0; mi < 4; ++mi)
        #pragma unroll
        for (int ni = 0; ni < 4; ++ni)
          acc[mi][ni] = __builtin_amdgcn_mfma_f32_16x16x32_bf16(af[mi], bfr[ni], acc[mi][ni], 0, 0, 0);
    }
  }
}

// ---------------- GEMM with fp32 output (+bias, optional gelu) ----------------
__global__ __launch_bounds__(256) void k_gemm_f32out(const short* __restrict__ A, const short* __restrict__ Bt,
                                                     float* __restrict__ Cout, const float* __restrict__ bias,
                                                     int N, int K, int doGelu)
{
  __shared__ short lds[2 * 128 * 64];
  f32x4 acc[4][4] = {};
  int m0 = blockIdx.y * 128, n0 = blockIdx.x * 128;
  gemm_core(A, Bt, K, K, K, m0, n0, lds, lds + 128*64, acc);
  int lane = threadIdx.x & 63, w = threadIdx.x >> 6;
  int wr = (w>>1)*64, wc = (w&1)*64, lr4 = (lane>>4)*4, lc = lane & 15;
  #pragma unroll
  for (int mi = 0; mi < 4; ++mi)
    #pragma unroll
    for (int ni = 0; ni < 4; ++ni)
      #pragma unroll
      for (int r = 0; r < 4; ++r) {
        int row = m0 + wr + mi*16 + lr4 + r;
        int col = n0 + wc + ni*16 + lc;
        float v = acc[mi][ni][r] + bias[col];
        if (doGelu) v = gelu_f(v);
        Cout[(size_t)row * N + col] = v;
      }
}

// ---------------- fused QKV GEMM: x[4096,1024] @ Wqkv^T, heads epilogue ----------------
__global__ __launch_bounds__(256) void k_gemm_qkv(const short* __restrict__ xb, const short* __restrict__ wqkvt,
                                                  short* __restrict__ q, short* __restrict__ kk, short* __restrict__ vt)
{
  __shared__ short lds[128 * 136];
  f32x4 acc[4][4] = {};
  int m0 = blockIdx.y * 128, n0 = blockIdx.x * 128;
  gemm_core(xb, wqkvt, 1024, 1024, 1024, m0, n0, lds, lds + 128*64, acc);
  int tid = threadIdx.x, lane = tid & 63, w = tid >> 6;
  int wr = (w>>1)*64, wc = (w&1)*64, lr4 = (lane>>4)*4, lc = lane & 15;
  int bb = m0 >> 10, tm0 = m0 & 1023;
  int s = n0 >> 10, dn0 = n0 & 1023;
  if (s < 2) {
    short* dst = (s == 0) ? q : kk;
    #pragma unroll
    for (int mi = 0; mi < 4; ++mi)
      #pragma unroll
      for (int ni = 0; ni < 4; ++ni)
        #pragma unroll
        for (int r = 0; r < 4; ++r) {
          int t = tm0 + wr + mi*16 + lr4 + r;
          int dfull = dn0 + wc + ni*16 + lc;
          dst[((size_t)(bb*16 + (dfull >> 6)) * 1024 + t) * 64 + (dfull & 63)] = f2b(acc[mi][ni][r]);
        }
  } else {
    __syncthreads();
    #pragma unroll
    for (int mi = 0; mi < 4; ++mi)
      #pragma unroll
      for (int ni = 0; ni < 4; ++ni)
        #pragma unroll
        for (int r = 0; r < 4; ++r) {
          int ml = wr + mi*16 + lr4 + r;
          int nl = wc + ni*16 + lc;
          lds[nl * 136 + ml] = f2b(acc[mi][ni][r]);
        }
    __syncthreads();
    for (int i = tid; i < 128*128/8; i += 256) {
      int nl = i >> 4, mc = (i * 8) & 127;
      int dfull = dn0 + nl;
      *(s16x8*)&vt[(((size_t)(bb*16 + (dfull >> 6)) * 64 + (dfull & 63)) << 10) + tm0 + mc]
          = *(s16x8*)&lds[nl * 136 + mc];
    }
  }
}

// ---------------- scores: S[bh] = q[bh] @ k[bh]^T * 0.125, causal-zeroed, bf16 ----------------
__global__ __launch_bounds__(256) void k_gemm_scores(const short* __restrict__ q, const short* __restrict__ kk,
                                                     short* __restrict__ S)
{
  int nt = blockIdx.x, mt = blockIdx.y, bh = blockIdx.z;
  if (nt > mt) return;   // fully masked tiles: never written, never read
  __shared__ short lds[2 * 128 * 64];
  f32x4 acc[4][4] = {};
  const short* A  = q  + ((size_t)bh << 16);
  const short* Bt = kk + ((size_t)bh << 16);
  int m0 = mt * 128, n0 = nt * 128;
  gemm_core(A, Bt, 64, 64, 64, m0, n0, lds, lds + 128*64, acc);
  short* Sp = S + ((size_t)bh << 20);
  int lane = threadIdx.x & 63, w = threadIdx.x >> 6;
  int wr = (w>>1)*64, wc = (w&1)*64, lr4 = (lane>>4)*4, lc = lane & 15;
  #pragma unroll
  for (int mi = 0; mi < 4; ++mi)
    #pragma unroll
    for (int ni = 0; ni < 4; ++ni)
      #pragma unroll
      for (int r = 0; r < 4; ++r) {
        int gm = m0 + wr + mi*16 + lr4 + r;
        int gn = n0 + wc + ni*16 + lc;
        float v = acc[mi][ni][r] * 0.125f;
        if (gn > gm) v = 0.0f;
        Sp[((size_t)gm << 10) + gn] = f2b(v);
      }
}

// ---------------- fused conv3x3 + mask + softmax + PV ----------------
__global__ __launch_bounds__(256) void k_conv_softmax_pv(const short* __restrict__ S, const short* __restrict__ vt,
                                                         const float* __restrict__ kern, short* __restrict__ O)
{
  constexpr int PSTR = 1032;           // shorts; 2064B row stride (16B aligned, conflict-reduced)
  __shared__ short p[16 * PSTR];
  int bh = blockIdx.y, b = bh >> 4, h = bh & 15;
  int q0 = blockIdx.x * 16;
  int tid = threadIdx.x;
  int g = tid >> 4, i = tid & 15;
  int qrow = q0 + g;
  int c0 = i * 64;
  const short* Sp = S + ((size_t)bh << 20);
  float wk[3][3];
  #pragma unroll
  for (int a = 0; a < 3; ++a)
    #pragma unroll
    for (int bj = 0; bj < 3; ++bj) wk[a][bj] = kern[bh*9 + a*3 + bj];

  float outv[64];
  #pragma unroll
  for (int j = 0; j < 8; ++j) {
    int c = c0 + j * 8;
    float accv[8] = {0,0,0,0,0,0,0,0};
    #pragma unroll
    for (int di = 0; di < 3; ++di) {
      int qq = qrow + di - 1;
      if (qq < 0 || qq > 1023) continue;
      if (c - 1 > qq) continue;                     // all taps masked
      float f[10];
      f[0] = (c >= 1 && c - 1 <= qq) ? b2f(Sp[((size_t)qq << 10) + c - 1]) : 0.0f;
      if (c <= qq) {
        s16x8 v8 = *(const s16x8*)&Sp[((size_t)qq << 10) + c];
        #pragma unroll
        for (int t = 0; t < 8; ++t) f[1 + t] = (c + t <= qq) ? b2f(v8[t]) : 0.0f;
      } else {
        #pragma unroll
        for (int t = 0; t < 8; ++t) f[1 + t] = 0.0f;
      }
      f[9] = (c + 8 <= qq) ? b2f(Sp[((size_t)qq << 10) + c + 8]) : 0.0f;
      #pragma unroll
      for (int t = 0; t < 8; ++t) accv[t] += wk[di][0]*f[t] + wk[di][1]*f[t+1] + wk[di][2]*f[t+2];
    }
    #pragma unroll
    for (int t = 0; t < 8; ++t) outv[j*8 + t] = accv[t];
  }
  // row softmax over valid cols (c <= qrow); row-group = 16 lanes
  float mx = -3.0e38f;
  #pragma unroll
  for (int t = 0; t < 64; ++t) if (c0 + t <= qrow) mx = fmaxf(mx, outv[t]);
  #pragma unroll
  for (int off = 1; off < 16; off <<= 1) mx = fmaxf(mx, __shfl_xor(mx, off));
  float sum = 0.0f;
  #pragma unroll
  for (int t = 0; t < 64; ++t) {
    float e = (c0 + t <= qrow) ? __expf(outv[t] - mx) : 0.0f;
    outv[t] = e; sum += e;
  }
  #pragma unroll
  for (int off = 1; off < 16; off <<= 1) sum += __shfl_xor(sum, off);
  float inv = 1.0f / sum;
  #pragma unroll
  for (int t = 0; t < 64; t += 8) {
    s16x8 o;
    #pragma unroll
    for (int u = 0; u < 8; ++u) o[u] = f2b(outv[t + u] * inv);
    *(s16x8*)&p[g * PSTR + c0 + t] = o;
  }
  __syncthreads();
  // PV: O_blk[16,64] = P[16,1024] @ V ; wave w does 16 output cols
  int lane = tid & 63, w = tid >> 6;
  int n0 = w * 16;
  int lr = lane & 15, lk = (lane >> 4) * 8;
  f32x4 acc = {0,0,0,0};
  int klim = ((q0 + 16 + 31) >> 5) << 5; if (klim > 1024) klim = 1024;
  for (int k0 = 0; k0 < klim; k0 += 32) {
    bf16x8 a  = *(bf16x8*)&p[lr * PSTR + k0 + lk];
    bf16x8 bv = *(const bf16x8*)&vt[(((size_t)bh * 64 + n0 + lr) << 10) + k0 + lk];
    acc = __builtin_amdgcn_mfma_f32_16x16x32_bf16(a, bv, acc, 0, 0, 0);
  }
  #pragma unroll
  for (int r = 0; r < 4; ++r) {
    int t = q0 + (lane >> 4) * 4 + r;
    int dfull = h * 64 + n0 + lr;
    O[((size_t)(b * 1024 + t) << 10) + dfull] = f2b(acc[r]);
  }
}

// ---------------- LN + gelu, fp32 in -> bf16 out (one row per block) ----------------
__global__ __launch_bounds__(256) void k_ln_gelu(const float* __restrict__ x, const float* __restrict__ g,
                                                 const float* __restrict__ be, short* __restrict__ out, int Cc)
{
  __shared__ float red[16];
  int row = blockIdx.x, tid = threadIdx.x;
  const float* xr = x + (size_t)row * Cc;
  float s = 0, s2 = 0;
  for (int c = tid; c < Cc; c += 256) { float v = xr[c]; s += v; s2 += v*v; }
  #pragma unroll
  for (int off = 32; off; off >>= 1) { s += __shfl_xor(s, off); s2 += __shfl_xor(s2, off); }
  if ((tid & 63) == 0) { red[tid >> 6] = s; red[8 + (tid >> 6)] = s2; }
  __syncthreads();
  s  = red[0] + red[1] + red[2] + red[3];
  s2 = red[8] + red[9] + red[10] + red[11];
  float mean = s / Cc;
  float var  = s2 / Cc - mean * mean;
  float inv  = rsqrtf(var + 1e-5f);
  for (int c = tid; c < Cc; c += 256) {
    float v = (xr[c] - mean) * inv * g[c] + be[c];
    out[(size_t)row * Cc + c] = f2b(gelu_f(v));
  }
}

// ---------------- aw logits: t[1024,512] . w2[512] + b2 (one wave per row) ----------------
__global__ __launch_bounds__(256) void k_aw_logit(const float* __restrict__ t, const float* __restrict__ w2,
                                                  const float* __restrict__ b2, float* __restrict__ logit)
{
  int row = blockIdx.x * 4 + (threadIdx.x >> 6);
  int lane = threadIdx.x & 63;
  float s = 0;
  for (int c = lane; c < 512; c += 64) s += t[(size_t)row * 512 + c] * w2[c];
  #pragma unroll
  for (int off = 32; off; off >>= 1) s += __shfl_xor(s, off);
  if (lane == 0) logit[row] = s + b2[0];
}

// ---------------- softmax over Th=256 per batch ----------------
__global__ __launch_bounds__(256) void k_softmax_aw(const float* __restrict__ logit, float* __restrict__ aw)
{
  __shared__ float red[8];
  int b = blockIdx.x, tid = threadIdx.x;
  float v = logit[b * 256 + tid];
  float m = v;
  #pragma unroll
  for (int off = 32; off; off >>= 1) m = fmaxf(m, __shfl_xor(m, off));
  if ((tid & 63) == 0) red[tid >> 6] = m;
  __syncthreads();
  m = fmaxf(fmaxf(red[0], red[1]), fmaxf(red[2], red[3]));
  float e = __expf(v - m);
  float s = e;
  #pragma unroll
  for (int off = 32; off; off >>= 1) s += __shfl_xor(s, off);
  if ((tid & 63) == 0) red[4 + (tid >> 6)] = s;
  __syncthreads();
  s = red[4] + red[5] + red[6] + red[7];
  aw[b * 256 + tid] = e / s;
}

// ---------------- cc[b,c] = sum_t aw[b,t] * eh[b,t,c] ----------------
__global__ __launch_bounds__(256) void k_cc(const short* __restrict__ ehb, const float* __restrict__ aw,
                                            float* __restrict__ cc)
{
  int b = blockIdx.y;
  int c = blockIdx.x * 256 + threadIdx.x;
  float s = 0;
  for (int t = 0; t < 256; ++t) s += aw[b * 256 + t] * b2f(ehb[(((size_t)b * 256 + t) << 11) + c]);
  cc[(b << 11) + c] = s;
}

// ---------------- kg1: cc[4,2048] @ kg_W1[2048,1024] + b1 (fp32) ----------------
__global__ __launch_bounds__(256) void k_kg1(const float* __restrict__ cc, const float* __restrict__ W1,
                                             const float* __restrict__ b1, float* __restrict__ outp)
{
  int b = blockIdx.y;
  int d = blockIdx.x * 256 + threadIdx.x;
  float s = b1[d];
  for (int k = 0; k < 2048; ++k) s += cc[(b << 11) + k] * W1[(size_t)k * 1024 + d];
  outp[b * 1024 + d] = s;
}

// ---------------- kp: kgh[4,1024](bf16) @ kg_W2[1024,144] + b2 ----------------
__global__ __launch_bounds__(256) void k_kp(const short* __restrict__ kgh, const float* __restrict__ W2,
                                            const float* __restrict__ b2, float* __restrict__ kp)
{
  int b = blockIdx.x, j = threadIdx.x;
  if (j >= 144) return;
  float s = b2[j];
  for (int k = 0; k < 1024; ++k) s += b2f(kgh[b * 1024 + k]) * W2[(size_t)k * 144 + j];
  kp[b * 144 + j] = s;
}

// ---------------- softmax over 9 per (b,h) ----------------
__global__ __launch_bounds__(64) void k_softmax9(const float* __restrict__ kp, float* __restrict__ kern)
{
  int bh = threadIdx.x;
  const float* pp = kp + bh * 9;
  float m = pp[0];
  #pragma unroll
  for (int i = 1; i < 9; ++i) m = fmaxf(m, pp[i]);
  float e[9], s = 0;
  #pragma unroll
  for (int i = 0; i < 9; ++i) { e[i] = __expf(pp[i] - m); s += e[i]; }
  #pragma unroll
  for (int i = 0; i < 9; ++i) kern[bh * 9 + i] = e[i] / s;
}

__global__ void k_fail(float* out){ out[threadIdx.x] = 1.0e9f; }

extern "C" void kernel_launch(void* const* d_in, const int* in_sizes, int n_in,
                              void* d_out, int out_size, void* d_ws, size_t ws_size,
                              hipStream_t stream) {
  (void)in_sizes; (void)n_in; (void)out_size;
  const float* x       = (const float*)d_in[0];
  const float* hist    = (const float*)d_in[1];
  const float* Wq      = (const float*)d_in[2];
  const float* Wk      = (const float*)d_in[3];
  const float* Wv      = (const float*)d_in[4];
  const float* hist_W  = (const float*)d_in[5];
  const float* hist_b  = (const float*)d_in[6];
  const float* hln_g   = (const float*)d_in[7];
  const float* hln_b   = (const float*)d_in[8];
  const float* ctx_W1  = (const float*)d_in[9];
  const float* ctx_b1  = (const float*)d_in[10];
  const float* ctx_W2  = (const float*)d_in[11];
  const float* ctx_b2  = (const float*)d_in[12];
  const float* kg_W1   = (const float*)d_in[13];
  const float* kg_b1   = (const float*)d_in[14];
  const float* kln_g   = (const float*)d_in[15];
  const float* kln_b   = (const float*)d_in[16];
  const float* kg_W2   = (const float*)d_in[17];
  const float* kg_b2   = (const float*)d_in[18];
  const float* proj_W  = (const float*)d_in[19];
  const float* proj_b  = (const float*)d_in[20];
  float* outp = (float*)d_out;

  char* wsb = (char*)d_ws;
  size_t off = 0;
  auto nxt = [&](size_t bytes) { void* p = wsb + off; off += (bytes + 255) & ~(size_t)255; return p; };

  short* xb     = (short*)nxt((size_t)4096*1024*2);
  short* wqkvt  = (short*)nxt((size_t)3*1024*1024*2);
  short* qb     = (short*)nxt((size_t)64*1024*64*2);
  short* kb     = (short*)nxt((size_t)64*1024*64*2);
  short* vtb    = (short*)nxt((size_t)64*64*1024*2);
  short* Sb     = (short*)nxt((size_t)64*1024*1024*2);
  short* Ob     = (short*)nxt((size_t)4096*1024*2);
  short* histb  = (short*)nxt((size_t)1024*1024*2);
  short* whtb   = (short*)nxt((size_t)2048*1024*2);
  float* ehpre  = (float*)nxt((size_t)1024*2048*4);
  short* ehb    = (short*)nxt((size_t)1024*2048*2);
  short* wc1tb  = (short*)nxt((size_t)512*2048*2);
  float* tbuf   = (float*)nxt((size_t)1024*512*4);
  float* logit  = (float*)nxt((size_t)1024*4);
  float* aw     = (float*)nxt((size_t)1024*4);
  float* ccb    = (float*)nxt((size_t)4*2048*4);
  float* kghpre = (float*)nxt((size_t)4*1024*4);
  short* kghb   = (short*)nxt((size_t)4*1024*2);
  float* kpb    = (float*)nxt((size_t)4*144*4);
  float* kernb  = (float*)nxt((size_t)64*9*4);
  short* wptb   = (short*)nxt((size_t)1024*1024*2);

  if (ws_size < off) { k_fail<<<1, 64, 0, stream>>>(outp); return; }

  // casts + weight transposes
  k_cast<<<2048, 256, 0, stream>>>(x, xb, 4096*1024);
  k_cast<<<512, 256, 0, stream>>>(hist, histb, 1024*1024);
  k_tcast<<<dim3(32, 32), 256, 0, stream>>>(Wq, wqkvt,               1024, 1024);
  k_tcast<<<dim3(32, 32), 256, 0, stream>>>(Wk, wqkvt + 1024*1024,   1024, 1024);
  k_tcast<<<dim3(32, 32), 256, 0, stream>>>(Wv, wqkvt + 2*1024*1024, 1024, 1024);
  k_tcast<<<dim3(64, 32), 256, 0, stream>>>(hist_W, whtb, 1024, 2048);
  k_tcast<<<dim3(16, 64), 256, 0, stream>>>(ctx_W1, wc1tb, 2048, 512);
  k_tcast<<<dim3(32, 32), 256, 0, stream>>>(proj_W, wptb, 1024, 1024);

  // context path
  k_gemm_f32out<<<dim3(16, 8), 256, 0, stream>>>(histb, whtb, ehpre, hist_b, 2048, 1024, 0);
  k_ln_gelu<<<1024, 256, 0, stream>>>(ehpre, hln_g, hln_b, ehb, 2048);
  k_gemm_f32out<<<dim3(4, 8), 256, 0, stream>>>(ehb, wc1tb, tbuf, ctx_b1, 512, 2048, 1);
  k_aw_logit<<<256, 256, 0, stream>>>(tbuf, ctx_W2, ctx_b2, logit);
  k_softmax_aw<<<4, 256, 0, stream>>>(logit, aw);
  k_cc<<<dim3(8, 4), 256, 0, stream>>>(ehb, aw, ccb);
  k_kg1<<<dim3(4, 4), 256, 0, stream>>>(ccb, kg_W1, kg_b1, kghpre);
  k_ln_gelu<<<4, 256, 0, stream>>>(kghpre, kln_g, kln_b, kghb, 1024);
  k_kp<<<4, 256, 0, stream>>>(kghb, kg_W2, kg_b2, kpb);
  k_softmax9<<<1, 64, 0, stream>>>(kpb, kernb);

  // attention path
  k_gemm_qkv<<<dim3(24, 32), 256, 0, stream>>>(xb, wqkvt, qb, kb, vtb);
  k_gemm_scores<<<dim3(8, 8, 64), 256, 0, stream>>>(qb, kb, Sb);
  k_conv_softmax_pv<<<dim3(64, 64), 256, 0, stream>>>(Sb, vtb, kernb, Ob);
  k_gemm_f32out<<<dim3(8, 32), 256, 0, stream>>>(Ob, wptb, outp, proj_b, 1024, 1024, 0);
}

// Round 2
// 358.893 us; speedup vs baseline: 1.5854x; 1.5854x over previous
//
#include <hip/hip_runtime.h>
#include <hip/hip_bf16.h>
#include <math.h>

#define DEV static __device__ __forceinline__

typedef __attribute__((ext_vector_type(4))) float f32x4;
typedef __attribute__((ext_vector_type(8))) __bf16 bf16x8;
typedef __attribute__((ext_vector_type(8))) short s16x8;

DEV float b2f(short v){ unsigned u = ((unsigned)(unsigned short)v) << 16; float f; __builtin_memcpy(&f, &u, 4); return f; }
DEV short f2b(float f){ unsigned u; __builtin_memcpy(&u, &f, 4); unsigned r = (u + 0x7fffu + ((u >> 16) & 1u)) >> 16; return (short)r; }
DEV float gelu_f(float v){ return 0.5f * v * (1.0f + erff(v * 0.70710678118654752f)); }

DEV void gload16(const void* g, void* l) {
  __builtin_amdgcn_global_load_lds((const __attribute__((address_space(1))) unsigned int*)g,
                                   (__attribute__((address_space(3))) unsigned int*)l, 16, 0, 0);
}

// ---------------- generic cast fp32 -> bf16 (n % 8 == 0) ----------------
__global__ __launch_bounds__(256) void k_cast(const float* __restrict__ in, short* __restrict__ out, int n){
  int i = (blockIdx.x * 256 + threadIdx.x) * 8;
  if (i >= n) return;
  f32x4 a = *(const f32x4*)&in[i];
  f32x4 b = *(const f32x4*)&in[i + 4];
  s16x8 o;
  o[0]=f2b(a[0]); o[1]=f2b(a[1]); o[2]=f2b(a[2]); o[3]=f2b(a[3]);
  o[4]=f2b(b[0]); o[5]=f2b(b[1]); o[6]=f2b(b[2]); o[7]=f2b(b[3]);
  *(s16x8*)&out[i] = o;
}

// ---------------- transpose-cast: W[K][N] fp32 -> Wt[N][K] bf16 (dims %32==0) ----------------
DEV void tcast_body(const float* __restrict__ W, short* __restrict__ Wt, int K, int N){
  __shared__ float tile[32][33];
  int nb = blockIdx.x * 32, kb = blockIdx.y * 32;
  int tid = threadIdx.x;
  int c = tid & 31, r0 = tid >> 5;
  #pragma unroll
  for (int r = r0; r < 32; r += 8) tile[r][c] = W[(size_t)(kb + r) * N + nb + c];
  __syncthreads();
  #pragma unroll
  for (int r = r0; r < 32; r += 8) Wt[(size_t)(nb + r) * K + kb + c] = f2b(tile[c][r]);
}
__global__ __launch_bounds__(256) void k_tcast(const float* __restrict__ W, short* __restrict__ Wt, int K, int N){
  tcast_body(W, Wt, K, N);
}
__global__ __launch_bounds__(256) void k_tcast3(const float* __restrict__ W0, const float* __restrict__ W1,
                                                const float* __restrict__ W2, short* __restrict__ Wt){
  const float* W = (blockIdx.z == 0) ? W0 : (blockIdx.z == 1) ? W1 : W2;
  tcast_body(W, Wt + (size_t)blockIdx.z * 1024 * 1024, 1024, 1024);
}

// ---------------- GEMM core: per-wave acc = A[m0:m0+128, :K] * Bt[n0:n0+128, :K]^T ----------------
DEV void gemm_core(const short* __restrict__ A, const short* __restrict__ Bt,
                   int K, int lda, int ldb, int m0, int n0,
                   short* lA, short* lB, f32x4 acc[4][4])
{
  const int tid = threadIdx.x;
  const int lane = tid & 63;
  const int w = tid >> 6;
  const int wr = (w >> 1) * 64, wc = (w & 1) * 64;
  const int lr = lane & 15, lk = (lane >> 4) * 8;
  for (int kt = 0; kt < K; kt += 64) {
    __syncthreads();
    #pragma unroll
    for (int i = 0; i < 4; ++i) {
      int off = i * 2048 + tid * 8;
      int r = off >> 6, c = off & 63;
      gload16(&A[(size_t)(m0 + r) * lda + kt + c], &lA[off]);
      gload16(&Bt[(size_t)(n0 + r) * ldb + kt + c], &lB[off]);
    }
    __syncthreads();
    #pragma unroll
    for (int kk = 0; kk < 64; kk += 32) {
      bf16x8 af[4], bfr[4];
      #pragma unroll
      for (int mi = 0; mi < 4; ++mi) af[mi] = *(bf16x8*)&lA[(wr + mi*16 + lr)*64 + kk + lk];
      #pragma unroll
      for (int ni = 0; ni < 4; ++ni) bfr[ni] = *(bf16x8*)&lB[(wc + ni*16 + lr)*64 + kk + lk];
      #pragma unroll
      for (int mi = 0; mi < 4; ++mi)
        #pragma unroll
        for (int ni = 0; ni < 4; ++ni)
          acc[mi][ni] = __builtin_amdgcn_mfma_f32_16x16x32_bf16(af[mi], bfr[ni], acc[mi][ni], 0, 0, 0);
    }
  }
}

// ---------------- GEMM with fp32 output (+bias, optional gelu) ----------------
__global__ __launch_bounds__(256) void k_gemm_f32out(const short* __restrict__ A, const short* __restrict__ Bt,
                                                     float* __restrict__ Cout, const float* __restrict__ bias,
                                                     int N, int K, int doGelu)
{
  __shared__ __align__(16) short lds[2 * 128 * 64];
  f32x4 acc[4][4] = {};
  int m0 = blockIdx.y * 128, n0 = blockIdx.x * 128;
  gemm_core(A, Bt, K, K, K, m0, n0, lds, lds + 128*64, acc);
  int lane = threadIdx.x & 63, w = threadIdx.x >> 6;
  int wr = (w>>1)*64, wc = (w&1)*64, lr4 = (lane>>4)*4, lc = lane & 15;
  #pragma unroll
  for (int mi = 0; mi < 4; ++mi)
    #pragma unroll
    for (int ni = 0; ni < 4; ++ni)
      #pragma unroll
      for (int r = 0; r < 4; ++r) {
        int row = m0 + wr + mi*16 + lr4 + r;
        int col = n0 + wc + ni*16 + lc;
        float v = acc[mi][ni][r] + bias[col];
        if (doGelu) v = gelu_f(v);
        Cout[(size_t)row * N + col] = v;
      }
}

// ---------------- fused QKV GEMM: x[4096,1024] @ Wqkv^T, heads epilogue ----------------
__global__ __launch_bounds__(256) void k_gemm_qkv(const short* __restrict__ xb, const short* __restrict__ wqkvt,
                                                  short* __restrict__ q, short* __restrict__ kk, short* __restrict__ vt)
{
  __shared__ __align__(16) short lds[128 * 136];
  f32x4 acc[4][4] = {};
  int m0 = blockIdx.y * 128, n0 = blockIdx.x * 128;
  gemm_core(xb, wqkvt, 1024, 1024, 1024, m0, n0, lds, lds + 128*64, acc);
  int tid = threadIdx.x, lane = tid & 63, w = tid >> 6;
  int wr = (w>>1)*64, wc = (w&1)*64, lr4 = (lane>>4)*4, lc = lane & 15;
  int bb = m0 >> 10, tm0 = m0 & 1023;
  int s = n0 >> 10, dn0 = n0 & 1023;
  if (s < 2) {
    short* dst = (s == 0) ? q : kk;
    #pragma unroll
    for (int mi = 0; mi < 4; ++mi)
      #pragma unroll
      for (int ni = 0; ni < 4; ++ni)
        #pragma unroll
        for (int r = 0; r < 4; ++r) {
          int t = tm0 + wr + mi*16 + lr4 + r;
          int dfull = dn0 + wc + ni*16 + lc;
          dst[((size_t)(bb*16 + (dfull >> 6)) * 1024 + t) * 64 + (dfull & 63)] = f2b(acc[mi][ni][r]);
        }
  } else {
    __syncthreads();
    #pragma unroll
    for (int mi = 0; mi < 4; ++mi)
      #pragma unroll
      for (int ni = 0; ni < 4; ++ni)
        #pragma unroll
        for (int r = 0; r < 4; ++r) {
          int ml = wr + mi*16 + lr4 + r;
          int nl = wc + ni*16 + lc;
          lds[nl * 136 + ml] = f2b(acc[mi][ni][r]);
        }
    __syncthreads();
    for (int i = tid; i < 128*128/8; i += 256) {
      int nl = i >> 4, mc = (i * 8) & 127;
      int dfull = dn0 + nl;
      *(s16x8*)&vt[(((size_t)(bb*16 + (dfull >> 6)) * 64 + (dfull & 63)) << 10) + tm0 + mc]
          = *(s16x8*)&lds[nl * 136 + mc];
    }
  }
}

// ---------------- scores: S = q@k^T * 0.125, causal-zeroed; nt==mt+1 tiles zero-filled ----------------
__global__ __launch_bounds__(256) void k_gemm_scores(const short* __restrict__ q, const short* __restrict__ kk,
                                                     short* __restrict__ S)
{
  int nt = blockIdx.x, mt = blockIdx.y, bh = blockIdx.z;
  if (nt > mt + 1) return;
  short* Sp = S + ((size_t)bh << 20);
  int m0 = mt * 128, n0 = nt * 128;
  if (nt == mt + 1) {           // zero border tile so conv can read unpredicated
    s16x8 zz = {};
    for (int t = threadIdx.x * 8; t < 128*128; t += 2048)
      *(s16x8*)&Sp[((size_t)(m0 + (t >> 7)) << 10) + n0 + (t & 127)] = zz;
    return;
  }
  __shared__ __align__(16) short lds[2 * 128 * 64];
  f32x4 acc[4][4] = {};
  const short* A  = q  + ((size_t)bh << 16);
  const short* Bt = kk + ((size_t)bh << 16);
  gemm_core(A, Bt, 64, 64, 64, m0, n0, lds, lds + 128*64, acc);
  int lane = threadIdx.x & 63, w = threadIdx.x >> 6;
  int wr = (w>>1)*64, wc = (w&1)*64, lr4 = (lane>>4)*4, lc = lane & 15;
  #pragma unroll
  for (int mi = 0; mi < 4; ++mi)
    #pragma unroll
    for (int ni = 0; ni < 4; ++ni)
      #pragma unroll
      for (int r = 0; r < 4; ++r) {
        int gm = m0 + wr + mi*16 + lr4 + r;
        int gn = n0 + wc + ni*16 + lc;
        float v = acc[mi][ni][r] * 0.125f;
        if (gn > gm) v = 0.0f;
        Sp[((size_t)gm << 10) + gn] = f2b(v);
      }
}

// ---------------- fused conv3x3 + mask + softmax + PV ----------------
constexpr int CPSTR = 1040;     // shorts; 2080B row stride; rows land 8 banks apart

DEV void conv_chunk(const short* sS, int rbase, int c, const float wk[3][3], float o[8]) {
  #pragma unroll
  for (int t = 0; t < 8; ++t) o[t] = 0.0f;
  #pragma unroll
  for (int dr = 0; dr < 3; ++dr) {
    int base = (rbase + dr) * CPSTR + 8 + c;
    s16x8 v = *(const s16x8*)&sS[base];
    float f[10];
    f[0] = b2f(sS[base - 1]);
    #pragma unroll
    for (int t = 0; t < 8; ++t) f[t + 1] = b2f(v[t]);
    f[9] = b2f(sS[base + 8]);
    float w0 = wk[dr][0], w1 = wk[dr][1], w2 = wk[dr][2];
    #pragma unroll
    for (int t = 0; t < 8; ++t) o[t] += w0 * f[t] + w1 * f[t + 1] + w2 * f[t + 2];
  }
}

__global__ __launch_bounds__(256, 4) void k_conv_softmax_pv(const short* __restrict__ S, const short* __restrict__ vt,
                                                            const float* __restrict__ kern, short* __restrict__ O)
{
  __shared__ __align__(16) short sS[18 * CPSTR];
  __shared__ float sInv[16];
  int bh = blockIdx.y, b = bh >> 4, h = bh & 15;
  int q0 = blockIdx.x * 16;
  int tid = threadIdx.x;
  int g = tid >> 4, i = tid & 15;
  int qrow = q0 + g;
  const short* Sp = S + ((size_t)bh << 20);
  int SCOLS = (((q0 + 16) >> 7) + 1) * 128; if (SCOLS > 1024) SCOLS = 1024;
  int nj = SCOLS >> 7;

  // ---- stage S rows q0-1 .. q0+16 into LDS (zero row pad; left/right col pad) ----
  s16x8 zz = {};
  int cpr = SCOLS >> 3;
  int nch = 18 * cpr;
  for (int t = tid; t < nch; t += 256) {
    int r = t / cpr;
    int col = (t - r * cpr) * 8;
    int qq = q0 - 1 + r;
    s16x8 v = zz;
    if (qq >= 0 && qq < 1024) v = *(const s16x8*)&Sp[((size_t)qq << 10) + col];
    *(s16x8*)&sS[r * CPSTR + 8 + col] = v;
  }
  if (tid < 18) {
    *(s16x8*)&sS[tid * CPSTR] = zz;
    *(s16x8*)&sS[tid * CPSTR + 8 + SCOLS] = zz;
  }
  float wk[3][3];
  #pragma unroll
  for (int a = 0; a < 3; ++a)
    #pragma unroll
    for (int bj = 0; bj < 3; ++bj) wk[a][bj] = kern[bh * 9 + a * 3 + bj];
  __syncthreads();

  // ---- pass A: row max ----
  float mx = -3.0e38f;
  #pragma unroll 8
  for (int j = 0; j < 8; ++j) if (j < nj) {
    int c = i * 8 + j * 128;
    float o[8]; conv_chunk(sS, g, c, wk, o);
    #pragma unroll
    for (int t = 0; t < 8; ++t) if (c + t <= qrow) mx = fmaxf(mx, o[t]);
  }
  #pragma unroll
  for (int off = 1; off < 16; off <<= 1) mx = fmaxf(mx, __shfl_xor(mx, off));

  // ---- pass B: recompute, exp, pack unnormalized P (bf16) ----
  float sum = 0.0f;
  s16x8 ps[8];
  #pragma unroll 8
  for (int j = 0; j < 8; ++j) if (j < nj) {
    int c = i * 8 + j * 128;
    float o[8]; conv_chunk(sS, g, c, wk, o);
    s16x8 po;
    #pragma unroll
    for (int t = 0; t < 8; ++t) {
      float e = (c + t <= qrow) ? __expf(o[t] - mx) : 0.0f;
      sum += e;
      po[t] = f2b(e);
    }
    ps[j] = po;
  }
  #pragma unroll
  for (int off = 1; off < 16; off <<= 1) sum += __shfl_xor(sum, off);
  __syncthreads();                    // all conv reads complete before overwrite

  // ---- write P over sS rows 0..15 ----
  #pragma unroll 8
  for (int j = 0; j < 8; ++j) if (j < nj)
    *(s16x8*)&sS[g * CPSTR + i * 8 + j * 128] = ps[j];
  if (i == 0) sInv[g] = 1.0f / sum;
  __syncthreads();

  // ---- PV: O_blk[16,64] = P[16,klim] @ V ----
  int lane = tid & 63, w = tid >> 6;
  int n0w = w * 16;
  int lr = lane & 15, lk = (lane >> 4) * 8;
  f32x4 acc = {0, 0, 0, 0};
  int klim = ((q0 + 16 + 31) >> 5) << 5;
  for (int k0 = 0; k0 < klim; k0 += 32) {
    bf16x8 a  = *(bf16x8*)&sS[lr * CPSTR + k0 + lk];
    bf16x8 bv = *(const bf16x8*)&vt[(((size_t)bh * 64 + n0w + lr) << 10) + k0 + lk];
    acc = __builtin_amdgcn_mfma_f32_16x16x32_bf16(a, bv, acc, 0, 0, 0);
  }
  int r0 = (lane >> 4) * 4;
  #pragma unroll
  for (int r = 0; r < 4; ++r) {
    int rw = r0 + r;
    float ov = acc[r] * sInv[rw];
    O[((size_t)(b * 1024 + q0 + rw) << 10) + h * 64 + n0w + lr] = f2b(ov);
  }
}

// ---------------- LN + gelu, fp32 in -> bf16 out (one row per block) ----------------
__global__ __launch_bounds__(256) void k_ln_gelu(const float* __restrict__ x, const float* __restrict__ g,
                                                 const float* __restrict__ be, short* __restrict__ out, int Cc)
{
  __shared__ float red[16];
  int row = blockIdx.x, tid = threadIdx.x;
  const float* xr = x + (size_t)row * Cc;
  float s = 0, s2 = 0;
  for (int c = tid; c < Cc; c += 256) { float v = xr[c]; s += v; s2 += v*v; }
  #pragma unroll
  for (int off = 32; off; off >>= 1) { s += __shfl_xor(s, off); s2 += __shfl_xor(s2, off); }
  if ((tid & 63) == 0) { red[tid >> 6] = s; red[8 + (tid >> 6)] = s2; }
  __syncthreads();
  s  = red[0] + red[1] + red[2] + red[3];
  s2 = red[8] + red[9] + red[10] + red[11];
  float mean = s / Cc;
  float var  = s2 / Cc - mean * mean;
  float inv  = rsqrtf(var + 1e-5f);
  for (int c = tid; c < Cc; c += 256) {
    float v = (xr[c] - mean) * inv * g[c] + be[c];
    out[(size_t)row * Cc + c] = f2b(gelu_f(v));
  }
}

// ---------------- aw logits: t[1024,512] . w2[512] + b2 (one wave per row) ----------------
__global__ __launch_bounds__(256) void k_aw_logit(const float* __restrict__ t, const float* __restrict__ w2,
                                                  const float* __restrict__ b2, float* __restrict__ logit)
{
  int row = blockIdx.x * 4 + (threadIdx.x >> 6);
  int lane = threadIdx.x & 63;
  float s = 0;
  for (int c = lane; c < 512; c += 64) s += t[(size_t)row * 512 + c] * w2[c];
  #pragma unroll
  for (int off = 32; off; off >>= 1) s += __shfl_xor(s, off);
  if (lane == 0) logit[row] = s + b2[0];
}

// ---------------- softmax over Th=256 per batch ----------------
__global__ __launch_bounds__(256) void k_softmax_aw(const float* __restrict__ logit, float* __restrict__ aw)
{
  __shared__ float red[8];
  int b = blockIdx.x, tid = threadIdx.x;
  float v = logit[b * 256 + tid];
  float m = v;
  #pragma unroll
  for (int off = 32; off; off >>= 1) m = fmaxf(m, __shfl_xor(m, off));
  if ((tid & 63) == 0) red[tid >> 6] = m;
  __syncthreads();
  m = fmaxf(fmaxf(red[0], red[1]), fmaxf(red[2], red[3]));
  float e = __expf(v - m);
  float s = e;
  #pragma unroll
  for (int off = 32; off; off >>= 1) s += __shfl_xor(s, off);
  if ((tid & 63) == 0) red[4 + (tid >> 6)] = s;
  __syncthreads();
  s = red[4] + red[5] + red[6] + red[7];
  aw[b * 256 + tid] = e / s;
}

// ---------------- cc[b,c] = sum_t aw[b,t] * eh[b,t,c] ----------------
__global__ __launch_bounds__(256) void k_cc(const short* __restrict__ ehb, const float* __restrict__ aw,
                                            float* __restrict__ cc)
{
  int b = blockIdx.y;
  int c = blockIdx.x * 256 + threadIdx.x;
  float s = 0;
  for (int t = 0; t < 256; ++t) s += aw[b * 256 + t] * b2f(ehb[(((size_t)b * 256 + t) << 11) + c]);
  cc[(b << 11) + c] = s;
}

// ---------------- kg1 split-K partials: part[kc][b][1024] ----------------
__global__ __launch_bounds__(256) void k_kg1p(const float* __restrict__ cc, const float* __restrict__ W1,
                                              float* __restrict__ part)
{
  int d = blockIdx.x * 256 + threadIdx.x;
  int kc = blockIdx.y;
  float s0 = 0, s1 = 0, s2 = 0, s3 = 0;
  for (int k = kc * 256; k < kc * 256 + 256; ++k) {
    float w = W1[(size_t)k * 1024 + d];
    s0 += cc[k] * w; s1 += cc[2048 + k] * w; s2 += cc[4096 + k] * w; s3 += cc[6144 + k] * w;
  }
  part[(size_t)(kc * 4 + 0) * 1024 + d] = s0;
  part[(size_t)(kc * 4 + 1) * 1024 + d] = s1;
  part[(size_t)(kc * 4 + 2) * 1024 + d] = s2;
  part[(size_t)(kc * 4 + 3) * 1024 + d] = s3;
}
__global__ __launch_bounds__(256) void k_kg1r(const float* __restrict__ part, const float* __restrict__ b1,
                                              float* __restrict__ outp)
{
  int idx = blockIdx.x * 256 + threadIdx.x;   // 4096
  int d = idx & 1023, b = idx >> 10;
  float s = b1[d];
  #pragma unroll
  for (int kc = 0; kc < 8; ++kc) s += part[(size_t)(kc * 4 + b) * 1024 + d];
  outp[idx] = s;
}

// ---------------- kp: one wave per (j,b) output ----------------
__global__ __launch_bounds__(256) void k_kp(const short* __restrict__ kgh, const float* __restrict__ W2,
                                            const float* __restrict__ b2, float* __restrict__ kp)
{
  int j = blockIdx.x * 4 + (threadIdx.x >> 6);
  int b = blockIdx.y;
  int lane = threadIdx.x & 63;
  float s = 0;
  for (int k = lane; k < 1024; k += 64) s += b2f(kgh[b * 1024 + k]) * W2[(size_t)k * 144 + j];
  #pragma unroll
  for (int off = 32; off; off >>= 1) s += __shfl_xor(s, off);
  if (lane == 0) kp[b * 144 + j] = s + b2[j];
}

// ---------------- softmax over 9 per (b,h) ----------------
__global__ __launch_bounds__(64) void k_softmax9(const float* __restrict__ kp, float* __restrict__ kern)
{
  int bh = threadIdx.x;
  const float* pp = kp + bh * 9;
  float m = pp[0];
  #pragma unroll
  for (int i = 1; i < 9; ++i) m = fmaxf(m, pp[i]);
  float e[9], s = 0;
  #pragma unroll
  for (int i = 0; i < 9; ++i) { e[i] = __expf(pp[i] - m); s += e[i]; }
  #pragma unroll
  for (int i = 0; i < 9; ++i) kern[bh * 9 + i] = e[i] / s;
}

__global__ void k_fail(float* out){ out[threadIdx.x] = 1.0e9f; }

extern "C" void kernel_launch(void* const* d_in, const int* in_sizes, int n_in,
                              void* d_out, int out_size, void* d_ws, size_t ws_size,
                              hipStream_t stream) {
  (void)in_sizes; (void)n_in; (void)out_size;
  const float* x       = (const float*)d_in[0];
  const float* hist    = (const float*)d_in[1];
  const float* Wq      = (const float*)d_in[2];
  const float* Wk      = (const float*)d_in[3];
  const float* Wv      = (const float*)d_in[4];
  const float* hist_W  = (const float*)d_in[5];
  const float* hist_b  = (const float*)d_in[6];
  const float* hln_g   = (const float*)d_in[7];
  const float* hln_b   = (const float*)d_in[8];
  const float* ctx_W1  = (const float*)d_in[9];
  const float* ctx_b1  = (const float*)d_in[10];
  const float* ctx_W2  = (const float*)d_in[11];
  const float* ctx_b2  = (const float*)d_in[12];
  const float* kg_W1   = (const float*)d_in[13];
  const float* kg_b1   = (const float*)d_in[14];
  const float* kln_g   = (const float*)d_in[15];
  const float* kln_b   = (const float*)d_in[16];
  const float* kg_W2   = (const float*)d_in[17];
  const float* kg_b2   = (const float*)d_in[18];
  const float* proj_W  = (const float*)d_in[19];
  const float* proj_b  = (const float*)d_in[20];
  float* outp = (float*)d_out;

  char* wsb = (char*)d_ws;
  size_t off = 0;
  auto nxt = [&](size_t bytes) { void* p = wsb + off; off += (bytes + 255) & ~(size_t)255; return p; };

  short* xb     = (short*)nxt((size_t)4096*1024*2);
  short* wqkvt  = (short*)nxt((size_t)3*1024*1024*2);
  short* qb     = (short*)nxt((size_t)64*1024*64*2);
  short* kb     = (short*)nxt((size_t)64*1024*64*2);
  short* vtb    = (short*)nxt((size_t)64*64*1024*2);
  short* Sb     = (short*)nxt((size_t)64*1024*1024*2);
  short* Ob     = (short*)nxt((size_t)4096*1024*2);
  short* histb  = (short*)nxt((size_t)1024*1024*2);
  short* whtb   = (short*)nxt((size_t)2048*1024*2);
  float* ehpre  = (float*)nxt((size_t)1024*2048*4);
  short* ehb    = (short*)nxt((size_t)1024*2048*2);
  short* wc1tb  = (short*)nxt((size_t)512*2048*2);
  float* tbuf   = (float*)nxt((size_t)1024*512*4);
  float* logit  = (float*)nxt((size_t)1024*4);
  float* aw     = (float*)nxt((size_t)1024*4);
  float* ccb    = (float*)nxt((size_t)4*2048*4);
  float* kgpart = (float*)nxt((size_t)32*1024*4);
  float* kghpre = (float*)nxt((size_t)4*1024*4);
  short* kghb   = (short*)nxt((size_t)4*1024*2);
  float* kpb    = (float*)nxt((size_t)4*144*4);
  float* kernb  = (float*)nxt((size_t)64*9*4);
  short* wptb   = (short*)nxt((size_t)1024*1024*2);

  if (ws_size < off) { k_fail<<<1, 64, 0, stream>>>(outp); return; }

  // casts + weight transposes
  k_cast<<<2048, 256, 0, stream>>>(x, xb, 4096*1024);
  k_cast<<<512, 256, 0, stream>>>(hist, histb, 1024*1024);
  k_tcast3<<<dim3(32, 32, 3), 256, 0, stream>>>(Wq, Wk, Wv, wqkvt);
  k_tcast<<<dim3(64, 32), 256, 0, stream>>>(hist_W, whtb, 1024, 2048);
  k_tcast<<<dim3(16, 64), 256, 0, stream>>>(ctx_W1, wc1tb, 2048, 512);
  k_tcast<<<dim3(32, 32), 256, 0, stream>>>(proj_W, wptb, 1024, 1024);

  // context path
  k_gemm_f32out<<<dim3(16, 8), 256, 0, stream>>>(histb, whtb, ehpre, hist_b, 2048, 1024, 0);
  k_ln_gelu<<<1024, 256, 0, stream>>>(ehpre, hln_g, hln_b, ehb, 2048);
  k_gemm_f32out<<<dim3(4, 8), 256, 0, stream>>>(ehb, wc1tb, tbuf, ctx_b1, 512, 2048, 1);
  k_aw_logit<<<256, 256, 0, stream>>>(tbuf, ctx_W2, ctx_b2, logit);
  k_softmax_aw<<<4, 256, 0, stream>>>(logit, aw);
  k_cc<<<dim3(8, 4), 256, 0, stream>>>(ehb, aw, ccb);
  k_kg1p<<<dim3(4, 8), 256, 0, stream>>>(ccb, kg_W1, kgpart);
  k_kg1r<<<16, 256, 0, stream>>>(kgpart, kg_b1, kghpre);
  k_ln_gelu<<<4, 256, 0, stream>>>(kghpre, kln_g, kln_b, kghb, 1024);
  k_kp<<<dim3(36, 4), 256, 0, stream>>>(kghb, kg_W2, kg_b2, kpb);
  k_softmax9<<<1, 64, 0, stream>>>(kpb, kernb);

  // attention path
  k_gemm_qkv<<<dim3(24, 32), 256, 0, stream>>>(xb, wqkvt, qb, kb, vtb);
  k_gemm_scores<<<dim3(8, 8, 64), 256, 0, stream>>>(qb, kb, Sb);
  k_conv_softmax_pv<<<dim3(64, 64), 256, 0, stream>>>(Sb, vtb, kernb, Ob);
  k_gemm_f32out<<<dim3(8, 32), 256, 0, stream>>>(Ob, wptb, outp, proj_b, 1024, 1024, 0);
}

// Round 3
// 343.227 us; speedup vs baseline: 1.6577x; 1.0456x over previous
//
#include <hip/hip_runtime.h>
#include <hip/hip_bf16.h>
#include <math.h>

#define DEV static __device__ __forceinline__

typedef __attribute__((ext_vector_type(4))) float f32x4;
typedef __attribute__((ext_vector_type(8))) __bf16 bf16x8;
typedef __attribute__((ext_vector_type(8))) short s16x8;
typedef __attribute__((ext_vector_type(2))) _Float16 h16x2;

DEV float b2f(short v){ unsigned u = ((unsigned)(unsigned short)v) << 16; float f; __builtin_memcpy(&f, &u, 4); return f; }
DEV short f2b(float f){ unsigned u; __builtin_memcpy(&u, &f, 4); unsigned r = (u + 0x7fffu + ((u >> 16) & 1u)) >> 16; return (short)r; }
DEV short f2h(float f){ _Float16 h = (_Float16)f; short s; __builtin_memcpy(&s, &h, 2); return s; }
DEV float h2f(short s){ _Float16 h; __builtin_memcpy(&h, &s, 2); return (float)h; }
DEV h16x2 u2h2(unsigned u){ h16x2 h; __builtin_memcpy(&h, &u, 4); return h; }
DEV float gelu_f(float v){ return 0.5f * v * (1.0f + erff(v * 0.70710678118654752f)); }

DEV void gload16(const void* g, void* l) {
  __builtin_amdgcn_global_load_lds((const __attribute__((address_space(1))) unsigned int*)g,
                                   (__attribute__((address_space(3))) unsigned int*)l, 16, 0, 0);
}

// ---------------- generic cast fp32 -> bf16 (n % 8 == 0) ----------------
__global__ __launch_bounds__(256) void k_cast(const float* __restrict__ in, short* __restrict__ out, int n){
  int i = (blockIdx.x * 256 + threadIdx.x) * 8;
  if (i >= n) return;
  f32x4 a = *(const f32x4*)&in[i];
  f32x4 b = *(const f32x4*)&in[i + 4];
  s16x8 o;
  o[0]=f2b(a[0]); o[1]=f2b(a[1]); o[2]=f2b(a[2]); o[3]=f2b(a[3]);
  o[4]=f2b(b[0]); o[5]=f2b(b[1]); o[6]=f2b(b[2]); o[7]=f2b(b[3]);
  *(s16x8*)&out[i] = o;
}

// ---------------- transpose-cast: W[K][N] fp32 -> Wt[N][K] bf16 (dims %32==0) ----------------
DEV void tcast_body(const float* __restrict__ W, short* __restrict__ Wt, int K, int N){
  __shared__ float tile[32][33];
  int nb = blockIdx.x * 32, kb = blockIdx.y * 32;
  int tid = threadIdx.x;
  int c = tid & 31, r0 = tid >> 5;
  #pragma unroll
  for (int r = r0; r < 32; r += 8) tile[r][c] = W[(size_t)(kb + r) * N + nb + c];
  __syncthreads();
  #pragma unroll
  for (int r = r0; r < 32; r += 8) Wt[(size_t)(nb + r) * K + kb + c] = f2b(tile[c][r]);
}
__global__ __launch_bounds__(256) void k_tcast(const float* __restrict__ W, short* __restrict__ Wt, int K, int N){
  tcast_body(W, Wt, K, N);
}
__global__ __launch_bounds__(256) void k_tcast3(const float* __restrict__ W0, const float* __restrict__ W1,
                                                const float* __restrict__ W2, short* __restrict__ Wt){
  const float* W = (blockIdx.z == 0) ? W0 : (blockIdx.z == 1) ? W1 : W2;
  tcast_body(W, Wt + (size_t)blockIdx.z * 1024 * 1024, 1024, 1024);
}

// ---------------- GEMM core: per-wave acc = A[m0:m0+128, :K] * Bt[n0:n0+128, :K]^T ----------------
DEV void gemm_core(const short* __restrict__ A, const short* __restrict__ Bt,
                   int K, int lda, int ldb, int m0, int n0,
                   short* lA, short* lB, f32x4 acc[4][4])
{
  const int tid = threadIdx.x;
  const int lane = tid & 63;
  const int w = tid >> 6;
  const int wr = (w >> 1) * 64, wc = (w & 1) * 64;
  const int lr = lane & 15, lk = (lane >> 4) * 8;
  for (int kt = 0; kt < K; kt += 64) {
    __syncthreads();
    #pragma unroll
    for (int i = 0; i < 4; ++i) {
      int off = i * 2048 + tid * 8;
      int r = off >> 6, c = off & 63;
      gload16(&A[(size_t)(m0 + r) * lda + kt + c], &lA[off]);
      gload16(&Bt[(size_t)(n0 + r) * ldb + kt + c], &lB[off]);
    }
    __syncthreads();
    #pragma unroll
    for (int kk = 0; kk < 64; kk += 32) {
      bf16x8 af[4], bfr[4];
      #pragma unroll
      for (int mi = 0; mi < 4; ++mi) af[mi] = *(bf16x8*)&lA[(wr + mi*16 + lr)*64 + kk + lk];
      #pragma unroll
      for (int ni = 0; ni < 4; ++ni) bfr[ni] = *(bf16x8*)&lB[(wc + ni*16 + lr)*64 + kk + lk];
      #pragma unroll
      for (int mi = 0; mi < 4; ++mi)
        #pragma unroll
        for (int ni = 0; ni < 4; ++ni)
          acc[mi][ni] = __builtin_amdgcn_mfma_f32_16x16x32_bf16(af[mi], bfr[ni], acc[mi][ni], 0, 0, 0);
    }
  }
}

// ---------------- GEMM with fp32 output (+bias, optional gelu) ----------------
__global__ __launch_bounds__(256) void k_gemm_f32out(const short* __restrict__ A, const short* __restrict__ Bt,
                                                     float* __restrict__ Cout, const float* __restrict__ bias,
                                                     int N, int K, int doGelu)
{
  __shared__ __align__(16) short lds[2 * 128 * 64];
  f32x4 acc[4][4] = {};
  int m0 = blockIdx.y * 128, n0 = blockIdx.x * 128;
  gemm_core(A, Bt, K, K, K, m0, n0, lds, lds + 128*64, acc);
  int lane = threadIdx.x & 63, w = threadIdx.x >> 6;
  int wr = (w>>1)*64, wc = (w&1)*64, lr4 = (lane>>4)*4, lc = lane & 15;
  #pragma unroll
  for (int mi = 0; mi < 4; ++mi)
    #pragma unroll
    for (int ni = 0; ni < 4; ++ni)
      #pragma unroll
      for (int r = 0; r < 4; ++r) {
        int row = m0 + wr + mi*16 + lr4 + r;
        int col = n0 + wc + ni*16 + lc;
        float v = acc[mi][ni][r] + bias[col];
        if (doGelu) v = gelu_f(v);
        Cout[(size_t)row * N + col] = v;
      }
}

// ---------------- fused QKV GEMM: x[4096,1024] @ Wqkv^T, heads epilogue ----------------
__global__ __launch_bounds__(256) void k_gemm_qkv(const short* __restrict__ xb, const short* __restrict__ wqkvt,
                                                  short* __restrict__ q, short* __restrict__ kk, short* __restrict__ vt)
{
  __shared__ __align__(16) short lds[128 * 136];
  f32x4 acc[4][4] = {};
  int m0 = blockIdx.y * 128, n0 = blockIdx.x * 128;
  gemm_core(xb, wqkvt, 1024, 1024, 1024, m0, n0, lds, lds + 128*64, acc);
  int tid = threadIdx.x, lane = tid & 63, w = tid >> 6;
  int wr = (w>>1)*64, wc = (w&1)*64, lr4 = (lane>>4)*4, lc = lane & 15;
  int bb = m0 >> 10, tm0 = m0 & 1023;
  int s = n0 >> 10, dn0 = n0 & 1023;
  if (s < 2) {
    short* dst = (s == 0) ? q : kk;
    #pragma unroll
    for (int mi = 0; mi < 4; ++mi)
      #pragma unroll
      for (int ni = 0; ni < 4; ++ni)
        #pragma unroll
        for (int r = 0; r < 4; ++r) {
          int t = tm0 + wr + mi*16 + lr4 + r;
          int dfull = dn0 + wc + ni*16 + lc;
          dst[((size_t)(bb*16 + (dfull >> 6)) * 1024 + t) * 64 + (dfull & 63)] = f2b(acc[mi][ni][r]);
        }
  } else {
    __syncthreads();
    #pragma unroll
    for (int mi = 0; mi < 4; ++mi)
      #pragma unroll
      for (int ni = 0; ni < 4; ++ni)
        #pragma unroll
        for (int r = 0; r < 4; ++r) {
          int ml = wr + mi*16 + lr4 + r;
          int nl = wc + ni*16 + lc;
          lds[nl * 136 + ml] = f2b(acc[mi][ni][r]);
        }
    __syncthreads();
    for (int i = tid; i < 128*128/8; i += 256) {
      int nl = i >> 4, mc = (i * 8) & 127;
      int dfull = dn0 + nl;
      *(s16x8*)&vt[(((size_t)(bb*16 + (dfull >> 6)) * 64 + (dfull & 63)) << 10) + tm0 + mc]
          = *(s16x8*)&lds[nl * 136 + mc];
    }
  }
}

// ---------------- scores: S = q@k^T * 0.125, causal-zeroed, FP16; nt==mt+1 tiles zero-filled ----------------
__global__ __launch_bounds__(256) void k_gemm_scores(const short* __restrict__ q, const short* __restrict__ kk,
                                                     short* __restrict__ S)
{
  int nt = blockIdx.x, mt = blockIdx.y, bh = blockIdx.z;
  if (nt > mt + 1) return;
  short* Sp = S + ((size_t)bh << 20);
  int m0 = mt * 128, n0 = nt * 128;
  if (nt == mt + 1) {           // zero border tile so conv can read unpredicated
    s16x8 zz = {};
    for (int t = threadIdx.x * 8; t < 128*128; t += 2048)
      *(s16x8*)&Sp[((size_t)(m0 + (t >> 7)) << 10) + n0 + (t & 127)] = zz;
    return;
  }
  __shared__ __align__(16) short lds[2 * 128 * 64];
  f32x4 acc[4][4] = {};
  const short* A  = q  + ((size_t)bh << 16);
  const short* Bt = kk + ((size_t)bh << 16);
  gemm_core(A, Bt, 64, 64, 64, m0, n0, lds, lds + 128*64, acc);
  int lane = threadIdx.x & 63, w = threadIdx.x >> 6;
  int wr = (w>>1)*64, wc = (w&1)*64, lr4 = (lane>>4)*4, lc = lane & 15;
  #pragma unroll
  for (int mi = 0; mi < 4; ++mi)
    #pragma unroll
    for (int ni = 0; ni < 4; ++ni)
      #pragma unroll
      for (int r = 0; r < 4; ++r) {
        int gm = m0 + wr + mi*16 + lr4 + r;
        int gn = n0 + wc + ni*16 + lc;
        float v = acc[mi][ni][r] * 0.125f;
        if (gn > gm) v = 0.0f;
        Sp[((size_t)gm << 10) + gn] = f2h(v);
      }
}

// ---------------- fused conv3x3 + mask + softmax + PV (S in f16) ----------------
constexpr int CPSTR = 1040;     // shorts; 2080B row stride

#if __has_builtin(__builtin_amdgcn_fdot2)
#define HAVE_FDOT2 1
#else
#define HAVE_FDOT2 0
#endif

// conv over one 8-col chunk, rows g..g+2 staged; S halves; weights packed f16
DEV void conv_chunk(const short* sS, int rbase, int c,
                    const h16x2 wp01[3], const h16x2 wp2z[3], float o[8]) {
  #pragma unroll
  for (int t = 0; t < 8; ++t) o[t] = 0.0f;
  #pragma unroll
  for (int dr = 0; dr < 3; ++dr) {
    int base = (rbase + dr) * CPSTR + 8 + c;
#if HAVE_FDOT2
    const unsigned* W = (const unsigned*)&sS[base];
    unsigned U0 = W[0], U1 = W[1], U2 = W[2], U3 = W[3];
    unsigned hm1 = (unsigned short)sS[base - 1];
    unsigned hp8 = (unsigned short)sS[base + 8];
    unsigned P0 = hm1 | (U0 << 16);
    unsigned P2 = (U0 >> 16) | (U1 << 16);
    unsigned P4 = (U1 >> 16) | (U2 << 16);
    unsigned P6 = (U2 >> 16) | (U3 << 16);
    unsigned P8 = (U3 >> 16) | (hp8 << 16);
    unsigned P9 = hp8;
    // pair[k] = (f[k], f[k+1]); out[t] += w01·pair[t] + w2z·pair[t+2]
    unsigned pr[10] = {P0, U0, P2, U1, P4, U2, P6, U3, P8, P9};
    h16x2 a = wp01[dr], bz = wp2z[dr];
    #pragma unroll
    for (int t = 0; t < 8; ++t) {
      o[t] = __builtin_amdgcn_fdot2(a,  u2h2(pr[t]),     o[t], false);
      o[t] = __builtin_amdgcn_fdot2(bz, u2h2(pr[t + 2]), o[t], false);
    }
#else
    float f[10];
    f[0] = h2f(sS[base - 1]);
    #pragma unroll
    for (int t = 0; t < 8; ++t) f[t + 1] = h2f(sS[base + t]);
    f[9] = h2f(sS[base + 8]);
    float w0 = (float)wp01[dr][0], w1 = (float)wp01[dr][1], w2 = (float)wp2z[dr][0];
    #pragma unroll
    for (int t = 0; t < 8; ++t) o[t] += w0 * f[t] + w1 * f[t + 1] + w2 * f[t + 2];
#endif
  }
}

__global__ __launch_bounds__(256, 4) void k_conv_softmax_pv(const short* __restrict__ S, const short* __restrict__ vt,
                                                            const float* __restrict__ kern, short* __restrict__ O)
{
  __shared__ __align__(16) short sS[18 * CPSTR];
  __shared__ float sInv[16];
  int bh = blockIdx.y, b = bh >> 4, h = bh & 15;
  int q0 = blockIdx.x * 16;
  int tid = threadIdx.x;
  int g = tid >> 4, i = tid & 15;
  int qrow = q0 + g;
  const short* Sp = S + ((size_t)bh << 20);
  int SCOLS = (((q0 + 16) >> 7) + 1) * 128; if (SCOLS > 1024) SCOLS = 1024;
  int nj = SCOLS >> 7;

  // ---- stage S rows q0-1 .. q0+16 into LDS (zero row pad; left/right col pad) ----
  s16x8 zz = {};
  {
    int r_off = tid >> 7;            // 0/1
    int col = (tid & 127) * 8;
    #pragma unroll
    for (int rr = 0; rr < 18; rr += 2) {
      int r = rr + r_off;
      if (col < SCOLS) {
        int qq = q0 - 1 + r;
        s16x8 v = zz;
        if (qq >= 0 && qq < 1024) v = *(const s16x8*)&Sp[((size_t)qq << 10) + col];
        *(s16x8*)&sS[r * CPSTR + 8 + col] = v;
      }
    }
  }
  if (tid < 18) {
    *(s16x8*)&sS[tid * CPSTR] = zz;
    *(s16x8*)&sS[tid * CPSTR + 8 + SCOLS] = zz;
  }
  h16x2 wp01[3], wp2z[3];
  #pragma unroll
  for (int a = 0; a < 3; ++a) {
    float w0 = kern[bh * 9 + a * 3 + 0];
    float w1 = kern[bh * 9 + a * 3 + 1];
    float w2 = kern[bh * 9 + a * 3 + 2];
    wp01[a][0] = (_Float16)w0; wp01[a][1] = (_Float16)w1;
    wp2z[a][0] = (_Float16)w2; wp2z[a][1] = (_Float16)0.0f;
  }
  __syncthreads();

  // ---- upper bound of row max: packed max over staged rows g..g+2 (convex-combination bound) ----
  h16x2 vm = {};          // zeros included (pads/masked entries are 0)
  #pragma unroll 3
  for (int r = 0; r < 3; ++r)
    #pragma unroll 8
    for (int j = 0; j < 8; ++j) if (j < nj) {
      const unsigned* W = (const unsigned*)&sS[(g + r) * CPSTR + 8 + i * 8 + j * 128];
      h16x2 a = __builtin_elementwise_max(u2h2(W[0]), u2h2(W[1]));
      h16x2 c = __builtin_elementwise_max(u2h2(W[2]), u2h2(W[3]));
      vm = __builtin_elementwise_max(vm, __builtin_elementwise_max(a, c));
    }
  float mx = fmaxf(fmaxf((float)vm[0], (float)vm[1]), 0.0f);
  #pragma unroll
  for (int off = 1; off < 16; off <<= 1) mx = fmaxf(mx, __shfl_xor(mx, off));

  // ---- single conv pass: conv, exp(o - mx), pack unnormalized P (bf16), sum ----
  float sum = 0.0f;
  s16x8 ps[8];
  #pragma unroll 8
  for (int j = 0; j < 8; ++j) if (j < nj) {
    int c = i * 8 + j * 128;
    float o[8]; conv_chunk(sS, g, c, wp01, wp2z, o);
    s16x8 po;
    #pragma unroll
    for (int t = 0; t < 8; ++t) {
      float e = (c + t <= qrow) ? __expf(o[t] - mx) : 0.0f;
      sum += e;
      po[t] = f2b(e);
    }
    ps[j] = po;
  }
  #pragma unroll
  for (int off = 1; off < 16; off <<= 1) sum += __shfl_xor(sum, off);
  __syncthreads();                    // all conv reads complete before overwrite

  // ---- write P over sS rows 0..15 ----
  #pragma unroll 8
  for (int j = 0; j < 8; ++j) if (j < nj)
    *(s16x8*)&sS[g * CPSTR + i * 8 + j * 128] = ps[j];
  if (i == 0) sInv[g] = 1.0f / sum;
  __syncthreads();

  // ---- PV: O_blk[16,64] = P[16,klim] @ V ----
  int lane = tid & 63, w = tid >> 6;
  int n0w = w * 16;
  int lr = lane & 15, lk = (lane >> 4) * 8;
  f32x4 acc = {0, 0, 0, 0};
  int klim = ((q0 + 16 + 31) >> 5) << 5;
  for (int k0 = 0; k0 < klim; k0 += 32) {
    bf16x8 a  = *(bf16x8*)&sS[lr * CPSTR + k0 + lk];
    bf16x8 bv = *(const bf16x8*)&vt[(((size_t)bh * 64 + n0w + lr) << 10) + k0 + lk];
    acc = __builtin_amdgcn_mfma_f32_16x16x32_bf16(a, bv, acc, 0, 0, 0);
  }
  int r0 = (lane >> 4) * 4;
  #pragma unroll
  for (int r = 0; r < 4; ++r) {
    int rw = r0 + r;
    float ov = acc[r] * sInv[rw];
    O[((size_t)(b * 1024 + q0 + rw) << 10) + h * 64 + n0w + lr] = f2b(ov);
  }
}

// ---------------- LN + gelu, fp32 in -> bf16 out (one row per block) ----------------
__global__ __launch_bounds__(256) void k_ln_gelu(const float* __restrict__ x, const float* __restrict__ g,
                                                 const float* __restrict__ be, short* __restrict__ out, int Cc)
{
  __shared__ float red[16];
  int row = blockIdx.x, tid = threadIdx.x;
  const float* xr = x + (size_t)row * Cc;
  float s = 0, s2 = 0;
  for (int c = tid; c < Cc; c += 256) { float v = xr[c]; s += v; s2 += v*v; }
  #pragma unroll
  for (int off = 32; off; off >>= 1) { s += __shfl_xor(s, off); s2 += __shfl_xor(s2, off); }
  if ((tid & 63) == 0) { red[tid >> 6] = s; red[8 + (tid >> 6)] = s2; }
  __syncthreads();
  s  = red[0] + red[1] + red[2] + red[3];
  s2 = red[8] + red[9] + red[10] + red[11];
  float mean = s / Cc;
  float var  = s2 / Cc - mean * mean;
  float inv  = rsqrtf(var + 1e-5f);
  for (int c = tid; c < Cc; c += 256) {
    float v = (xr[c] - mean) * inv * g[c] + be[c];
    out[(size_t)row * Cc + c] = f2b(gelu_f(v));
  }
}

// ---------------- aw logits: t[1024,512] . w2[512] + b2 (one wave per row) ----------------
__global__ __launch_bounds__(256) void k_aw_logit(const float* __restrict__ t, const float* __restrict__ w2,
                                                  const float* __restrict__ b2, float* __restrict__ logit)
{
  int row = blockIdx.x * 4 + (threadIdx.x >> 6);
  int lane = threadIdx.x & 63;
  float s = 0;
  for (int c = lane; c < 512; c += 64) s += t[(size_t)row * 512 + c] * w2[c];
  #pragma unroll
  for (int off = 32; off; off >>= 1) s += __shfl_xor(s, off);
  if (lane == 0) logit[row] = s + b2[0];
}

// ---------------- softmax over Th=256 per batch ----------------
__global__ __launch_bounds__(256) void k_softmax_aw(const float* __restrict__ logit, float* __restrict__ aw)
{
  __shared__ float red[8];
  int b = blockIdx.x, tid = threadIdx.x;
  float v = logit[b * 256 + tid];
  float m = v;
  #pragma unroll
  for (int off = 32; off; off >>= 1) m = fmaxf(m, __shfl_xor(m, off));
  if ((tid & 63) == 0) red[tid >> 6] = m;
  __syncthreads();
  m = fmaxf(fmaxf(red[0], red[1]), fmaxf(red[2], red[3]));
  float e = __expf(v - m);
  float s = e;
  #pragma unroll
  for (int off = 32; off; off >>= 1) s += __shfl_xor(s, off);
  if ((tid & 63) == 0) red[4 + (tid >> 6)] = s;
  __syncthreads();
  s = red[4] + red[5] + red[6] + red[7];
  aw[b * 256 + tid] = e / s;
}

// ---------------- cc[b,c] = sum_t aw[b,t] * eh[b,t,c] ----------------
__global__ __launch_bounds__(256) void k_cc(const short* __restrict__ ehb, const float* __restrict__ aw,
                                            float* __restrict__ cc)
{
  int b = blockIdx.y;
  int c = blockIdx.x * 256 + threadIdx.x;
  float s = 0;
  for (int t = 0; t < 256; ++t) s += aw[b * 256 + t] * b2f(ehb[(((size_t)b * 256 + t) << 11) + c]);
  cc[(b << 11) + c] = s;
}

// ---------------- kg1 split-K partials: part[kc][b][1024] ----------------
__global__ __launch_bounds__(256) void k_kg1p(const float* __restrict__ cc, const float* __restrict__ W1,
                                              float* __restrict__ part)
{
  int d = blockIdx.x * 256 + threadIdx.x;
  int kc = blockIdx.y;
  float s0 = 0, s1 = 0, s2 = 0, s3 = 0;
  for (int k = kc * 256; k < kc * 256 + 256; ++k) {
    float w = W1[(size_t)k * 1024 + d];
    s0 += cc[k] * w; s1 += cc[2048 + k] * w; s2 += cc[4096 + k] * w; s3 += cc[6144 + k] * w;
  }
  part[(size_t)(kc * 4 + 0) * 1024 + d] = s0;
  part[(size_t)(kc * 4 + 1) * 1024 + d] = s1;
  part[(size_t)(kc * 4 + 2) * 1024 + d] = s2;
  part[(size_t)(kc * 4 + 3) * 1024 + d] = s3;
}
__global__ __launch_bounds__(256) void k_kg1r(const float* __restrict__ part, const float* __restrict__ b1,
                                              float* __restrict__ outp)
{
  int idx = blockIdx.x * 256 + threadIdx.x;   // 4096
  int d = idx & 1023, b = idx >> 10;
  float s = b1[d];
  #pragma unroll
  for (int kc = 0; kc < 8; ++kc) s += part[(size_t)(kc * 4 + b) * 1024 + d];
  outp[idx] = s;
}

// ---------------- kp: one wave per (j,b) output ----------------
__global__ __launch_bounds__(256) void k_kp(const short* __restrict__ kgh, const float* __restrict__ W2,
                                            const float* __restrict__ b2, float* __restrict__ kp)
{
  int j = blockIdx.x * 4 + (threadIdx.x >> 6);
  int b = blockIdx.y;
  int lane = threadIdx.x & 63;
  float s = 0;
  for (int k = lane; k < 1024; k += 64) s += b2f(kgh[b * 1024 + k]) * W2[(size_t)k * 144 + j];
  #pragma unroll
  for (int off = 32; off; off >>= 1) s += __shfl_xor(s, off);
  if (lane == 0) kp[b * 144 + j] = s + b2[j];
}

// ---------------- softmax over 9 per (b,h) ----------------
__global__ __launch_bounds__(64) void k_softmax9(const float* __restrict__ kp, float* __restrict__ kern)
{
  int bh = threadIdx.x;
  const float* pp = kp + bh * 9;
  float m = pp[0];
  #pragma unroll
  for (int i = 1; i < 9; ++i) m = fmaxf(m, pp[i]);
  float e[9], s = 0;
  #pragma unroll
  for (int i = 0; i < 9; ++i) { e[i] = __expf(pp[i] - m); s += e[i]; }
  #pragma unroll
  for (int i = 0; i < 9; ++i) kern[bh * 9 + i] = e[i] / s;
}

__global__ void k_fail(float* out){ out[threadIdx.x] = 1.0e9f; }

extern "C" void kernel_launch(void* const* d_in, const int* in_sizes, int n_in,
                              void* d_out, int out_size, void* d_ws, size_t ws_size,
                              hipStream_t stream) {
  (void)in_sizes; (void)n_in; (void)out_size;
  const float* x       = (const float*)d_in[0];
  const float* hist    = (const float*)d_in[1];
  const float* Wq      = (const float*)d_in[2];
  const float* Wk      = (const float*)d_in[3];
  const float* Wv      = (const float*)d_in[4];
  const float* hist_W  = (const float*)d_in[5];
  const float* hist_b  = (const float*)d_in[6];
  const float* hln_g   = (const float*)d_in[7];
  const float* hln_b   = (const float*)d_in[8];
  const float* ctx_W1  = (const float*)d_in[9];
  const float* ctx_b1  = (const float*)d_in[10];
  const float* ctx_W2  = (const float*)d_in[11];
  const float* ctx_b2  = (const float*)d_in[12];
  const float* kg_W1   = (const float*)d_in[13];
  const float* kg_b1   = (const float*)d_in[14];
  const float* kln_g   = (const float*)d_in[15];
  const float* kln_b   = (const float*)d_in[16];
  const float* kg_W2   = (const float*)d_in[17];
  const float* kg_b2   = (const float*)d_in[18];
  const float* proj_W  = (const float*)d_in[19];
  const float* proj_b  = (const float*)d_in[20];
  float* outp = (float*)d_out;

  char* wsb = (char*)d_ws;
  size_t off = 0;
  auto nxt = [&](size_t bytes) { void* p = wsb + off; off += (bytes + 255) & ~(size_t)255; return p; };

  short* xb     = (short*)nxt((size_t)4096*1024*2);
  short* wqkvt  = (short*)nxt((size_t)3*1024*1024*2);
  short* qb     = (short*)nxt((size_t)64*1024*64*2);
  short* kb     = (short*)nxt((size_t)64*1024*64*2);
  short* vtb    = (short*)nxt((size_t)64*64*1024*2);
  short* Sb     = (short*)nxt((size_t)64*1024*1024*2);
  short* Ob     = (short*)nxt((size_t)4096*1024*2);
  short* histb  = (short*)nxt((size_t)1024*1024*2);
  short* whtb   = (short*)nxt((size_t)2048*1024*2);
  float* ehpre  = (float*)nxt((size_t)1024*2048*4);
  short* ehb    = (short*)nxt((size_t)1024*2048*2);
  short* wc1tb  = (short*)nxt((size_t)512*2048*2);
  float* tbuf   = (float*)nxt((size_t)1024*512*4);
  float* logit  = (float*)nxt((size_t)1024*4);
  float* aw     = (float*)nxt((size_t)1024*4);
  float* ccb    = (float*)nxt((size_t)4*2048*4);
  float* kgpart = (float*)nxt((size_t)32*1024*4);
  float* kghpre = (float*)nxt((size_t)4*1024*4);
  short* kghb   = (short*)nxt((size_t)4*1024*2);
  float* kpb    = (float*)nxt((size_t)4*144*4);
  float* kernb  = (float*)nxt((size_t)64*9*4);
  short* wptb   = (short*)nxt((size_t)1024*1024*2);

  if (ws_size < off) { k_fail<<<1, 64, 0, stream>>>(outp); return; }

  // casts + weight transposes
  k_cast<<<2048, 256, 0, stream>>>(x, xb, 4096*1024);
  k_cast<<<512, 256, 0, stream>>>(hist, histb, 1024*1024);
  k_tcast3<<<dim3(32, 32, 3), 256, 0, stream>>>(Wq, Wk, Wv, wqkvt);
  k_tcast<<<dim3(64, 32), 256, 0, stream>>>(hist_W, whtb, 1024, 2048);
  k_tcast<<<dim3(16, 64), 256, 0, stream>>>(ctx_W1, wc1tb, 2048, 512);
  k_tcast<<<dim3(32, 32), 256, 0, stream>>>(proj_W, wptb, 1024, 1024);

  // context path
  k_gemm_f32out<<<dim3(16, 8), 256, 0, stream>>>(histb, whtb, ehpre, hist_b, 2048, 1024, 0);
  k_ln_gelu<<<1024, 256, 0, stream>>>(ehpre, hln_g, hln_b, ehb, 2048);
  k_gemm_f32out<<<dim3(4, 8), 256, 0, stream>>>(ehb, wc1tb, tbuf, ctx_b1, 512, 2048, 1);
  k_aw_logit<<<256, 256, 0, stream>>>(tbuf, ctx_W2, ctx_b2, logit);
  k_softmax_aw<<<4, 256, 0, stream>>>(logit, aw);
  k_cc<<<dim3(8, 4), 256, 0, stream>>>(ehb, aw, ccb);
  k_kg1p<<<dim3(4, 8), 256, 0, stream>>>(ccb, kg_W1, kgpart);
  k_kg1r<<<16, 256, 0, stream>>>(kgpart, kg_b1, kghpre);
  k_ln_gelu<<<4, 256, 0, stream>>>(kghpre, kln_g, kln_b, kghb, 1024);
  k_kp<<<dim3(36, 4), 256, 0, stream>>>(kghb, kg_W2, kg_b2, kpb);
  k_softmax9<<<1, 64, 0, stream>>>(kpb, kernb);

  // attention path
  k_gemm_qkv<<<dim3(24, 32), 256, 0, stream>>>(xb, wqkvt, qb, kb, vtb);
  k_gemm_scores<<<dim3(8, 8, 64), 256, 0, stream>>>(qb, kb, Sb);
  k_conv_softmax_pv<<<dim3(64, 64), 256, 0, stream>>>(Sb, vtb, kernb, Ob);
  k_gemm_f32out<<<dim3(8, 32), 256, 0, stream>>>(Ob, wptb, outp, proj_b, 1024, 1024, 0);
}